// Round 9
// baseline (244.776 us; speedup 1.0000x reference)
//
#include <hip/hip_runtime.h>
#include <hip/hip_cooperative_groups.h>
#include <math.h>

namespace cg = cooperative_groups;

#define KOBJ 256
#define NB   256              // grid blocks == CUs; 1 block/CU co-resident (cooperative)
#define QMIN 0.5f
#define BETA_CLIP_C (1.0f - 1e-5f)

typedef unsigned long long u64;

struct Params {
    const float*  pred_beta;
    const float2* pred_ccoords;
    const float*  pred_energy;
    const float2* pred_pos;
    const float*  pred_time;
    const float2* pred_id2;
    const float*  t_energy;
    const float2* t_pos;
    const float*  t_time;
    const int*    t_idx;
    float4* pts4;        // [n] packed (x, y, q, idx-bits)
    u64*    pk_part;     // [K][NB]
    float*  cnt_part;    // [K][NB]
    float*  den_part;    // [K][NB]
    float*  num_part;    // [K][NB]
    float*  noise_part;  // [NB]
    float4* objA;        // [K] (xk, yk, qa, lb); qa==0 => invalid
    float*  accum;       // [8]: s0, n_valid, cnt_sum, noise_sum, counter
    float*  rep_part;    // [K][NB]
    float*  att_part;    // [K][NB]
    float*  out;
    int n;
    int cpb;             // points per block for heavy phase = ceil(n/NB)
};

__global__ __launch_bounds__(256, 1) void oc_all(Params p) {
    cg::grid_group grid = cg::this_grid();
    __shared__ u64   spk[256];
    __shared__ float sA[256], sB[256], sC[256], sD[256], sE[256];
    __shared__ float4 pts[256];
    const int t = threadIdx.x;
    const int b = blockIdx.x;
    const int n = p.n;

    // ============ phase 1: per-point compute, LDS accumulation, packed pts4 ============
    spk[t] = 0; sA[t] = 0.f; sB[t] = 0.f; sC[t] = 0.f;   // cnt, den, num
    if (b == 0 && t < 8) p.accum[t] = 0.f;
    __syncthreads();
    float noise = 0.f;
    for (int i = b * 256 + t; i < n; i += NB * 256) {
        int tid = p.t_idx[i];
        float braw = p.pred_beta[i];
        float beta = fminf(fmaxf(braw, 0.f), BETA_CLIP_C);
        float at = atanhf(beta);
        float2 cc = p.pred_ccoords[i];
        p.pts4[i] = make_float4(cc.x, cc.y, at * at + QMIN, __int_as_float(tid));
        if (tid >= 0) {
            atomicAdd(&sA[tid], 1.0f);
            u64 key = ((u64)__float_as_uint(beta) << 32) |
                      (u64)(0x7FFFFFFFu - (unsigned)i);   // max beta, tie -> lowest index
            atomicMax(&spk[tid], key);
            float te = p.t_energy[i];
            float ew = (te > 10.0f) ? 1.0f : fmaxf(0.0f, (te - 0.5f) / 9.5f);
            float de = te - p.pred_energy[i];
            float el = de * de / (te + 1.0f);
            float2 tp = p.t_pos[i];
            float2 pp = p.pred_pos[i];
            float dpx = tp.x - pp.x, dpy = tp.y - pp.y;
            float pl = (dpx * dpx + dpy * dpy) * 0.01f;
            float dt = p.t_time[i] - p.pred_time[i];
            float tl = dt * dt;
            float2 id0 = p.pred_id2[3 * i];
            float2 id1 = p.pred_id2[3 * i + 1];
            float2 id2 = p.pred_id2[3 * i + 2];
            float cs = id0.x * id0.x + id0.y * id0.y + id1.x * id1.x +
                       id1.y * id1.y + id2.x * id2.x + id2.y * id2.y;
            cs *= (1e-8f / 6.0f);
            float mask = (braw < 0.1f) ? 0.0f : 1.0f;  // PAYLOAD_BETA_CLIP on raw beta
            float w = mask * ew * beta;
            atomicAdd(&sB[tid], beta);
            atomicAdd(&sC[tid], (el + pl + tl + cs) * w);
        } else {
            noise += beta;
        }
    }
    __syncthreads();
    p.pk_part[t * NB + b]  = spk[t];   // k-major rows, coalesced consumers
    p.cnt_part[t * NB + b] = sA[t];
    p.den_part[t * NB + b] = sB[t];
    p.num_part[t * NB + b] = sC[t];
    sD[t] = noise;
    __syncthreads();
    for (int s = 128; s > 0; s >>= 1) {
        if (t < s) sD[t] += sD[t + s];
        __syncthreads();
    }
    if (t == 0) p.noise_part[b] = sD[0];
    grid.sync();

    // ============ phase 2: block k merges pk row -> objA[k] ============
    {
        const int k = b;
        spk[t] = p.pk_part[k * NB + t];
        __syncthreads();
        for (int s = 128; s > 0; s >>= 1) {
            if (t < s) { u64 q = spk[t + s]; if (q > spk[t]) spk[t] = q; }
            __syncthreads();
        }
        if (t == 0) {
            u64 pk = spk[0];
            float4 oa = make_float4(0.f, 0.f, 0.f, 0.f);
            if (pk != 0) {
                unsigned a = 0x7FFFFFFFu - (unsigned)(pk & 0xFFFFFFFFull);
                float ba = __uint_as_float((unsigned)(pk >> 32));
                float2 cc = p.pred_ccoords[a];
                float at = atanhf(ba);
                oa = make_float4(cc.x, cc.y, at * at + QMIN, 1.0f - ba);
            }
            p.objA[k] = oa;
        }
    }
    grid.sync();

    // ============ phase 3: heavy N x K, balanced contiguous ranges ============
    {
        float4 oa = p.objA[t];
        float xk = oa.x, yk = oa.y;
        float rep = 0.f, att = 0.f;
        int lo = b * p.cpb;
        int hi = min(n, lo + p.cpb);
        for (int base = lo; base < hi; base += 256) {
            int jcnt = min(256, hi - base);           // wave-uniform trim
            __syncthreads();
            if (t < jcnt) pts[t] = p.pts4[base + t];  // coalesced stage load
            __syncthreads();
            for (int j = 0; j < jcnt; ++j) {
                float4 s = pts[j];                    // uniform-address broadcast
                float dx = s.x - xk, dy = s.y - yk;
                float d2 = fmaf(dx, dx, dy * dy);
                float r = __builtin_amdgcn_sqrtf(d2 + 1e-6f);
                float h = fmaxf(0.f, 1.f - r);
                bool own = (__float_as_int(s.w) == t);
                rep = fmaf(own ? 0.f : h,  s.z, rep);
                att = fmaf(own ? d2 : 0.f, s.z, att);
            }
        }
        p.rep_part[t * NB + b] = rep;
        p.att_part[t * NB + b] = att;
    }
    grid.sync();

    // ============ phase 4: block k final reduce + atomic accumulate + last-block out ============
    {
        const int k = b;
        float* sF = (float*)pts;   // reuse as 6th reduction array
        sA[t] = p.rep_part[k * NB + t];
        sB[t] = p.att_part[k * NB + t];
        sC[t] = p.cnt_part[k * NB + t];
        sD[t] = p.den_part[k * NB + t];
        sE[t] = p.num_part[k * NB + t];
        sF[t] = (k == 0) ? p.noise_part[t] : 0.f;
        __syncthreads();
        for (int s = 128; s > 0; s >>= 1) {
            if (t < s) {
                sA[t] += sA[t + s]; sB[t] += sB[t + s]; sC[t] += sC[t + s];
                sD[t] += sD[t + s]; sE[t] += sE[t + s]; sF[t] += sF[t + s];
            }
            __syncthreads();
        }
        if (t == 0) {
            float cnt = sC[0];
            float s0 = 0.f, valid = 0.f;
            if (cnt > 0.f) {
                float4 oa = p.objA[k];
                float qa = oa.z, lb = oa.w;
                float pay = sE[0] / fmaxf(sD[0], 1e-6f);
                float vatt = sB[0] * qa / fmaxf(cnt, 1.f);
                float vrep = sA[0] * qa / fmaxf((float)n - cnt, 1.f);
                s0 = vatt + vrep + lb + pay;
                valid = 1.f;
            }
            atomicAdd(&p.accum[0], s0);
            atomicAdd(&p.accum[1], valid);
            atomicAdd(&p.accum[2], cnt);
            if (k == 0) atomicAdd(&p.accum[3], sF[0]);
            __threadfence();
            int prev = atomicAdd((int*)&p.accum[4], 1);
            if (prev == NB - 1) {
                __threadfence();
                volatile float* va = p.accum;
                float nv = fmaxf(va[1], 1.f);
                float nnoise = fmaxf((float)n - va[2], 1.f);
                p.out[0] = va[0] / nv + va[3] / nnoise;
            }
        }
    }
}

extern "C" void kernel_launch(void* const* d_in, const int* in_sizes, int n_in,
                              void* d_out, int out_size, void* d_ws, size_t ws_size,
                              hipStream_t stream) {
    int n = in_sizes[0];
    int cpb = (n + NB - 1) / NB;        // 391 for n=100000
    int npad = cpb * NB;

    char* base = (char*)d_ws;
    size_t off = 0;
    float4* pts4       = (float4*)(base + off); off += (size_t)npad * 16;        // 1.6 MB
    u64*    pk_part    = (u64*)   (base + off); off += (size_t)KOBJ * NB * 8;    // 512 KB
    float*  cnt_part   = (float*) (base + off); off += (size_t)KOBJ * NB * 4;    // 256 KB
    float*  den_part   = (float*) (base + off); off += (size_t)KOBJ * NB * 4;    // 256 KB
    float*  num_part   = (float*) (base + off); off += (size_t)KOBJ * NB * 4;    // 256 KB
    float*  noise_part = (float*) (base + off); off += NB * 4;
    float4* objA       = (float4*)(base + off); off += KOBJ * 16;
    float*  accum      = (float*) (base + off); off += 64;
    float*  rep_part   = (float*) (base + off); off += (size_t)KOBJ * NB * 4;    // 256 KB
    float*  att_part   = (float*) (base + off); off += (size_t)KOBJ * NB * 4;    // 256 KB

    Params p;
    p.pred_beta    = (const float*)d_in[0];
    p.pred_ccoords = (const float2*)d_in[1];
    p.pred_energy  = (const float*)d_in[2];
    p.pred_pos     = (const float2*)d_in[3];
    p.pred_time    = (const float*)d_in[4];
    p.pred_id2     = (const float2*)d_in[5];
    p.t_energy     = (const float*)d_in[6];
    p.t_pos        = (const float2*)d_in[7];
    p.t_time       = (const float*)d_in[8];
    p.t_idx        = (const int*)d_in[10];
    p.pts4 = pts4; p.pk_part = pk_part; p.cnt_part = cnt_part;
    p.den_part = den_part; p.num_part = num_part; p.noise_part = noise_part;
    p.objA = objA; p.accum = accum; p.rep_part = rep_part; p.att_part = att_part;
    p.out = (float*)d_out; p.n = n; p.cpb = cpb;

    void* args[] = { &p };
    hipLaunchCooperativeKernel((const void*)oc_all, dim3(NB), dim3(256), args, 0, stream);
}

// Round 10
// 116.608 us; speedup vs baseline: 2.0991x; 2.0991x over previous
//
#include <hip/hip_runtime.h>
#include <hip/hip_bf16.h>
#include <math.h>

#define KOBJ 256
#define B1   256              // partial-accumulator blocks
#define QMIN 0.5f
#define BETA_CLIP_C (1.0f - 1e-5f)

typedef unsigned long long u64;

// accum layout (floats): [0]=s0 sum, [1]=n_valid, [2]=cnt sum, [3]=noise sum, [4]=counter(int bits)

// ---------------- Kernel A: per-block LDS accumulation, k-major transposed partial writes
__global__ __launch_bounds__(256) void partials(
    const float*  __restrict__ pred_beta,
    const float*  __restrict__ pred_energy,
    const float2* __restrict__ pred_pos,
    const float*  __restrict__ pred_time,
    const float2* __restrict__ pred_id2,
    const float*  __restrict__ t_energy,
    const float2* __restrict__ t_pos,
    const float*  __restrict__ t_time,
    const int*    __restrict__ t_idx,
    u64*    __restrict__ pk_part,   // [K][B1]
    float*  __restrict__ cnt_part,  // [K][B1]
    float*  __restrict__ den_part,  // [K][B1]
    float*  __restrict__ num_part,  // [K][B1]
    float*  __restrict__ noise_part,// [B1]
    float*  __restrict__ accum,     // [8] zeroed here (block 0)
    int n)
{
    __shared__ u64   spk[KOBJ];
    __shared__ float scnt[KOBJ];
    __shared__ float sden[KOBJ], snum[KOBJ];
    __shared__ float snoise[256];
    int t = threadIdx.x;
    int b = blockIdx.x;
    spk[t] = 0; scnt[t] = 0.f; sden[t] = 0.f; snum[t] = 0.f;
    if (b == 0 && t < 8) accum[t] = 0.0f;
    __syncthreads();

    float noise = 0.0f;
    for (int i = b * 256 + t; i < n; i += B1 * 256) {
        int tid = t_idx[i];
        float braw = pred_beta[i];
        float beta = fminf(fmaxf(braw, 0.0f), BETA_CLIP_C);
        if (tid >= 0) {
            atomicAdd(&scnt[tid], 1.0f);
            u64 key = ((u64)__float_as_uint(beta) << 32) |
                      (u64)(0x7FFFFFFFu - (unsigned)i);   // max beta, tie -> lowest index
            atomicMax(&spk[tid], key);
            float te = t_energy[i];
            float ew = (te > 10.0f) ? 1.0f : fmaxf(0.0f, (te - 0.5f) / 9.5f);
            float de = te - pred_energy[i];
            float el = de * de / (te + 1.0f);
            float2 tp = t_pos[i];
            float2 pp = pred_pos[i];
            float dpx = tp.x - pp.x, dpy = tp.y - pp.y;
            float pl = (dpx * dpx + dpy * dpy) * 0.01f;
            float dt = t_time[i] - pred_time[i];
            float tl = dt * dt;
            float2 id0 = pred_id2[3 * i];
            float2 id1 = pred_id2[3 * i + 1];
            float2 id2 = pred_id2[3 * i + 2];
            float cs = id0.x * id0.x + id0.y * id0.y + id1.x * id1.x +
                       id1.y * id1.y + id2.x * id2.x + id2.y * id2.y;
            cs *= (1e-8f / 6.0f);
            float mask = (braw < 0.1f) ? 0.0f : 1.0f;  // PAYLOAD_BETA_CLIP on raw beta
            float w = mask * ew * beta;
            atomicAdd(&sden[tid], beta);
            atomicAdd(&snum[tid], (el + pl + tl + cs) * w);
        } else {
            noise += beta;
        }
    }
    __syncthreads();
    int o = t * B1 + b;
    pk_part[o]  = spk[t];
    cnt_part[o] = scnt[t];
    den_part[o] = sden[t];
    num_part[o] = snum[t];
    snoise[t] = noise;
    __syncthreads();
    for (int s = 128; s > 0; s >>= 1) {
        if (t < s) snoise[t] += snoise[t + s];
        __syncthreads();
    }
    if (t == 0) noise_part[b] = snoise[0];
}

// ---------------- Kernel B: one block per object; coalesced row reduce
__global__ __launch_bounds__(256) void merge(
    const float2* __restrict__ pred_ccoords,
    const u64*    __restrict__ pk_part,
    const float*  __restrict__ cnt_part,
    const float*  __restrict__ den_part,
    const float*  __restrict__ num_part,
    float4* __restrict__ objA,   // (xk, yk, qa, cnt)
    float4* __restrict__ objB)   // (pay, lb, valid, 0)
{
    __shared__ u64   spk[256];
    __shared__ float scnt[256], sden[256], snum[256];
    int k = blockIdx.x;
    int b = threadIdx.x;
    int o = k * B1 + b;
    u64 pk = pk_part[o];
    float cnt = cnt_part[o];
    float den = den_part[o];
    float nsum = num_part[o];
    spk[b] = pk; scnt[b] = cnt; sden[b] = den; snum[b] = nsum;
    __syncthreads();
    for (int s = 128; s > 0; s >>= 1) {
        if (b < s) {
            u64 p = spk[b + s]; if (p > spk[b]) spk[b] = p;
            scnt[b] += scnt[b + s];
            sden[b] += sden[b + s];
            snum[b] += snum[b + s];
        }
        __syncthreads();
    }
    if (b == 0) {
        float cs = scnt[0];
        bool valid = cs > 0.f;
        float xk = 0.f, yk = 0.f, qa = 0.f, lb = 0.f, pay = 0.f;
        if (valid) {
            u64 p = spk[0];
            unsigned a = 0x7FFFFFFFu - (unsigned)(p & 0xFFFFFFFFull);
            float ba = __uint_as_float((unsigned)(p >> 32));
            float2 cc = pred_ccoords[a];
            xk = cc.x; yk = cc.y;
            float at = atanhf(ba);
            qa = at * at + QMIN;
            lb = 1.0f - ba;
            pay = snum[0] / fmaxf(sden[0], 1e-6f);
        }
        objA[k] = make_float4(xk, yk, qa, cs);
        objB[k] = make_float4(pay, lb, valid ? 1.f : 0.f, 0.f);
    }
}

// ---------------- Kernel C: N x K hinge/attraction; k-major float2 partial writes
__global__ __launch_bounds__(256) void heavy(
    const float*  __restrict__ pred_beta,
    const float2* __restrict__ pred_ccoords,
    const int*    __restrict__ t_idx,
    const float4* __restrict__ objA,
    float2* __restrict__ ra_part,   // [K][hstr] (rep, att)
    int n, int hstr)
{
    __shared__ float4 pts[256];
    int t = threadIdx.x;
    int p = blockIdx.x * 256 + t;
    float4 pt;
    if (p < n) {
        float beta = fminf(fmaxf(pred_beta[p], 0.0f), BETA_CLIP_C);
        float at = atanhf(beta);
        float2 cc = pred_ccoords[p];
        pt = make_float4(cc.x, cc.y, at * at + QMIN, __int_as_float(t_idx[p]));
    } else {
        pt = make_float4(0.f, 0.f, 0.f, __int_as_float(-2));  // q=0 => inert
    }
    pts[t] = pt;
    float4 oa = objA[t];
    float xk = oa.x, yk = oa.y;
    __syncthreads();
    float rep = 0.f, att = 0.f;
    #pragma unroll 8
    for (int j = 0; j < 256; ++j) {
        float4 s = pts[j];                    // wave-uniform address -> bank broadcast
        float dx = s.x - xk, dy = s.y - yk;
        float d2 = fmaf(dy, dy, fmaf(dx, dx, 1e-6f));  // eps folded (att error ~1e-6*qq, negligible)
        float r = __builtin_amdgcn_sqrtf(d2);
        float h = fmaxf(0.0f, 1.0f - r);
        bool own = (__float_as_int(s.w) == t);
        rep = fmaf(own ? 0.0f : h,  s.z, rep);
        att = fmaf(own ? d2 : 0.0f, s.z, att);
    }
    ra_part[t * hstr + blockIdx.x] = make_float2(rep, att);
}

// ---------------- Kernel D: per-object finish + last-block scalar write
__global__ __launch_bounds__(256) void final_k(
    const float4* __restrict__ objA,
    const float4* __restrict__ objB,
    const float2* __restrict__ ra_part,
    const float*  __restrict__ noise_part,
    float* __restrict__ accum,
    float* __restrict__ out,
    int n, int nbh, int hstr)
{
    __shared__ float srep[256], satt[256], snoi[256];
    int k = blockIdx.x;
    int t = threadIdx.x;
    float rep = 0.f, att = 0.f;
    int o = k * hstr + t;
    if (t < nbh)        { float2 v = ra_part[o];       rep += v.x; att += v.y; }
    if (t + 256 < nbh)  { float2 v = ra_part[o + 256]; rep += v.x; att += v.y; }
    srep[t] = rep; satt[t] = att;
    snoi[t] = (k == 0) ? noise_part[t] : 0.f;
    __syncthreads();
    for (int s = 128; s > 0; s >>= 1) {
        if (t < s) { srep[t] += srep[t + s]; satt[t] += satt[t + s]; snoi[t] += snoi[t + s]; }
        __syncthreads();
    }
    if (t == 0) {
        float4 a  = objA[k];
        float4 b4 = objB[k];
        float cnt = a.w, qa = a.z, valid = b4.z;
        float vatt = valid * satt[0] * qa / fmaxf(cnt, 1.0f);
        float vrep = valid * srep[0] * qa / fmaxf((float)n - cnt, 1.0f);
        float s0 = vatt + vrep + b4.y + b4.x;
        atomicAdd(&accum[0], s0);
        atomicAdd(&accum[1], valid);
        atomicAdd(&accum[2], cnt);
        if (k == 0) atomicAdd(&accum[3], snoi[0]);
        __threadfence();
        int prev = atomicAdd((int*)&accum[4], 1);
        if (prev == KOBJ - 1) {              // last block: all adds visible
            __threadfence();
            volatile float* va = accum;
            float nv = fmaxf(va[1], 1.0f);
            float nnoise = fmaxf((float)n - va[2], 1.0f);
            out[0] = va[0] / nv + va[3] / nnoise;
        }
    }
}

extern "C" void kernel_launch(void* const* d_in, const int* in_sizes, int n_in,
                              void* d_out, int out_size, void* d_ws, size_t ws_size,
                              hipStream_t stream) {
    const float*  pred_beta    = (const float*)d_in[0];
    const float2* pred_ccoords = (const float2*)d_in[1];
    const float*  pred_energy  = (const float*)d_in[2];
    const float2* pred_pos     = (const float2*)d_in[3];
    const float*  pred_time    = (const float*)d_in[4];
    const float2* pred_id2     = (const float2*)d_in[5];
    const float*  t_energy     = (const float*)d_in[6];
    const float2* t_pos        = (const float2*)d_in[7];
    const float*  t_time       = (const float*)d_in[8];
    const int*    t_idx        = (const int*)d_in[10];
    int n = in_sizes[0];
    int nbh = (n + 255) / 256;          // 391 for n=100000
    int hstr = (nbh + 8) & ~7;          // padded row stride (392)

    // workspace carve (16B-aligned)
    char* base = (char*)d_ws;
    size_t off = 0;
    u64*    pk_part    = (u64*)   (base + off); off += (size_t)KOBJ * B1 * 8;    // 512 KB
    float*  cnt_part   = (float*) (base + off); off += (size_t)KOBJ * B1 * 4;    // 256 KB
    float*  den_part   = (float*) (base + off); off += (size_t)KOBJ * B1 * 4;    // 256 KB
    float*  num_part   = (float*) (base + off); off += (size_t)KOBJ * B1 * 4;    // 256 KB
    float*  noise_part = (float*) (base + off); off += 256 * 4;
    float4* objA       = (float4*)(base + off); off += KOBJ * 16;
    float4* objB       = (float4*)(base + off); off += KOBJ * 16;
    float*  accum      = (float*) (base + off); off += 64;
    float2* ra_part    = (float2*)(base + off); off += (size_t)KOBJ * hstr * 8;  // ~800 KB

    partials<<<B1, 256, 0, stream>>>(pred_beta, pred_energy, pred_pos, pred_time,
                                     pred_id2, t_energy, t_pos, t_time, t_idx,
                                     pk_part, cnt_part, den_part, num_part, noise_part,
                                     accum, n);
    merge<<<KOBJ, 256, 0, stream>>>(pred_ccoords, pk_part, cnt_part, den_part, num_part,
                                    objA, objB);
    heavy<<<nbh, 256, 0, stream>>>(pred_beta, pred_ccoords, t_idx, objA,
                                   ra_part, n, hstr);
    final_k<<<KOBJ, 256, 0, stream>>>(objA, objB, ra_part, noise_part, accum,
                                      (float*)d_out, n, nbh, hstr);
}

// Round 11
// 104.857 us; speedup vs baseline: 2.3344x; 1.1121x over previous
//
#include <hip/hip_runtime.h>
#include <hip/hip_bf16.h>
#include <math.h>

#define KOBJ 256
#define B1   256              // partial-accumulator blocks
#define NW   4                // waves per block
#define WSTR 257              // per-wave bucket stride (bank-conflict pad)
#define QMIN 0.5f
#define BETA_CLIP_C (1.0f - 1e-5f)

typedef unsigned long long u64;

// ---------------- Kernel A: per-block LDS accumulation with PER-WAVE buckets
// (removes same-address inter-wave atomic serialization), k-major partial writes.
__global__ __launch_bounds__(256) void partials(
    const float*  __restrict__ pred_beta,
    const float*  __restrict__ pred_energy,
    const float2* __restrict__ pred_pos,
    const float*  __restrict__ pred_time,
    const float2* __restrict__ pred_id2,
    const float*  __restrict__ t_energy,
    const float2* __restrict__ t_pos,
    const float*  __restrict__ t_time,
    const int*    __restrict__ t_idx,
    u64*    __restrict__ pk_part,   // [K][B1]
    float*  __restrict__ cnt_part,  // [K][B1]
    float*  __restrict__ den_part,  // [K][B1]
    float*  __restrict__ num_part,  // [K][B1]
    float*  __restrict__ noise_part,// [B1]
    int n)
{
    __shared__ u64   spk[NW][WSTR];                   // 8.2 KB
    __shared__ float scnt[NW][WSTR], sden[NW][WSTR], snum[NW][WSTR]; // 12.3 KB
    __shared__ float snoise[256];
    int t = threadIdx.x;
    int b = blockIdx.x;
    int w = t >> 6;
    for (int i = t; i < NW * WSTR; i += 256) {
        ((u64*)spk)[i] = 0;
        ((float*)scnt)[i] = 0.f;
        ((float*)sden)[i] = 0.f;
        ((float*)snum)[i] = 0.f;
    }
    __syncthreads();

    float noise = 0.0f;
    for (int i = b * 256 + t; i < n; i += B1 * 256) {
        int tid = t_idx[i];
        float braw = pred_beta[i];
        float beta = fminf(fmaxf(braw, 0.0f), BETA_CLIP_C);
        if (tid >= 0) {
            atomicAdd(&scnt[w][tid], 1.0f);
            u64 key = ((u64)__float_as_uint(beta) << 32) |
                      (u64)(0x7FFFFFFFu - (unsigned)i);   // max beta, tie -> lowest index
            atomicMax(&spk[w][tid], key);
            float te = t_energy[i];
            float ew = (te > 10.0f) ? 1.0f : fmaxf(0.0f, (te - 0.5f) / 9.5f);
            float de = te - pred_energy[i];
            float el = de * de / (te + 1.0f);
            float2 tp = t_pos[i];
            float2 pp = pred_pos[i];
            float dpx = tp.x - pp.x, dpy = tp.y - pp.y;
            float pl = (dpx * dpx + dpy * dpy) * 0.01f;
            float dt = t_time[i] - pred_time[i];
            float tl = dt * dt;
            float2 id0 = pred_id2[3 * i];
            float2 id1 = pred_id2[3 * i + 1];
            float2 id2 = pred_id2[3 * i + 2];
            float cs = id0.x * id0.x + id0.y * id0.y + id1.x * id1.x +
                       id1.y * id1.y + id2.x * id2.x + id2.y * id2.y;
            cs *= (1e-8f / 6.0f);
            float mask = (braw < 0.1f) ? 0.0f : 1.0f;  // PAYLOAD_BETA_CLIP on raw beta
            float wgt = mask * ew * beta;
            atomicAdd(&sden[w][tid], beta);
            atomicAdd(&snum[w][tid], (el + pl + tl + cs) * wgt);
        } else {
            noise += beta;
        }
    }
    __syncthreads();
    // fold 4 wave-buckets -> 1 (stride-1 reads, conflict-free)
    u64 pk = spk[0][t];
    { u64 q = spk[1][t]; if (q > pk) pk = q; }
    { u64 q = spk[2][t]; if (q > pk) pk = q; }
    { u64 q = spk[3][t]; if (q > pk) pk = q; }
    float cnt = scnt[0][t] + scnt[1][t] + scnt[2][t] + scnt[3][t];
    float den = sden[0][t] + sden[1][t] + sden[2][t] + sden[3][t];
    float num = snum[0][t] + snum[1][t] + snum[2][t] + snum[3][t];
    int o = t * B1 + b;
    pk_part[o]  = pk;
    cnt_part[o] = cnt;
    den_part[o] = den;
    num_part[o] = num;
    snoise[t] = noise;
    __syncthreads();
    for (int s = 128; s > 0; s >>= 1) {
        if (t < s) snoise[t] += snoise[t + s];
        __syncthreads();
    }
    if (t == 0) noise_part[b] = snoise[0];
}

// ---------------- Kernel B: one block per object; coalesced row reduce
__global__ __launch_bounds__(256) void merge(
    const float2* __restrict__ pred_ccoords,
    const u64*    __restrict__ pk_part,
    const float*  __restrict__ cnt_part,
    const float*  __restrict__ den_part,
    const float*  __restrict__ num_part,
    float4* __restrict__ objA,   // (xk, yk, qa, cnt)
    float4* __restrict__ objB)   // (pay, lb, valid, 0)
{
    __shared__ u64   spk[256];
    __shared__ float scnt[256], sden[256], snum[256];
    int k = blockIdx.x;
    int b = threadIdx.x;
    int o = k * B1 + b;
    u64 pk = pk_part[o];
    float cnt = cnt_part[o];
    float den = den_part[o];
    float nsum = num_part[o];
    spk[b] = pk; scnt[b] = cnt; sden[b] = den; snum[b] = nsum;
    __syncthreads();
    for (int s = 128; s > 0; s >>= 1) {
        if (b < s) {
            u64 p = spk[b + s]; if (p > spk[b]) spk[b] = p;
            scnt[b] += scnt[b + s];
            sden[b] += sden[b + s];
            snum[b] += snum[b + s];
        }
        __syncthreads();
    }
    if (b == 0) {
        float cs = scnt[0];
        bool valid = cs > 0.f;
        float xk = 0.f, yk = 0.f, qa = 0.f, lb = 0.f, pay = 0.f;
        if (valid) {
            u64 p = spk[0];
            unsigned a = 0x7FFFFFFFu - (unsigned)(p & 0xFFFFFFFFull);
            float ba = __uint_as_float((unsigned)(p >> 32));
            float2 cc = pred_ccoords[a];
            xk = cc.x; yk = cc.y;
            float at = atanhf(ba);
            qa = at * at + QMIN;
            lb = 1.0f - ba;
            pay = snum[0] / fmaxf(sden[0], 1e-6f);
        }
        objA[k] = make_float4(xk, yk, qa, cs);
        objB[k] = make_float4(pay, lb, valid ? 1.f : 0.f, 0.f);
    }
}

// ---------------- Kernel C (R8-proven): N x K hinge/attraction; k-major partial writes
__global__ __launch_bounds__(256) void heavy(
    const float*  __restrict__ pred_beta,
    const float2* __restrict__ pred_ccoords,
    const int*    __restrict__ t_idx,
    const float4* __restrict__ objA,
    float* __restrict__ rep_part,   // [K][hstr]
    float* __restrict__ att_part,   // [K][hstr]
    int n, int hstr)
{
    __shared__ float4 pts[256];
    int t = threadIdx.x;
    int p = blockIdx.x * 256 + t;
    float4 pt;
    if (p < n) {
        float beta = fminf(fmaxf(pred_beta[p], 0.0f), BETA_CLIP_C);
        float at = atanhf(beta);
        float2 cc = pred_ccoords[p];
        pt = make_float4(cc.x, cc.y, at * at + QMIN, __int_as_float(t_idx[p]));
    } else {
        pt = make_float4(0.f, 0.f, 0.f, __int_as_float(-2));  // q=0 => inert
    }
    pts[t] = pt;
    float4 oa = objA[t];
    float xk = oa.x, yk = oa.y;
    __syncthreads();
    float rep = 0.f, att = 0.f;
    #pragma unroll 8
    for (int j = 0; j < 256; ++j) {
        float4 s = pts[j];                    // wave-uniform address -> bank broadcast
        float dx = s.x - xk, dy = s.y - yk;
        float d2 = fmaf(dy, dy, fmaf(dx, dx, 1e-6f));  // eps folded (att err ~1e-6*qq)
        float r = __builtin_amdgcn_sqrtf(d2);
        float h = fmaxf(0.0f, 1.0f - r);
        bool own = (__float_as_int(s.w) == t);
        rep = fmaf(own ? 0.0f : h,  s.z, rep);
        att = fmaf(own ? d2 : 0.0f, s.z, att);
    }
    int o = t * hstr + blockIdx.x;
    rep_part[o] = rep;
    att_part[o] = att;
}

// ---------------- Kernel D1: per-object reduce of heavy partials (coalesced rows)
__global__ __launch_bounds__(256) void final1(
    const float4* __restrict__ objA,
    const float4* __restrict__ objB,
    const float*  __restrict__ rep_part,
    const float*  __restrict__ att_part,
    float4* __restrict__ objC,   // (s0, valid, cnt, 0)
    int n, int nbh, int hstr)
{
    __shared__ float srep[256], satt[256];
    int k = blockIdx.x;
    int b = threadIdx.x;
    float rep = 0.f, att = 0.f;
    int o = k * hstr + b;
    if (b < nbh)        { rep += rep_part[o];        att += att_part[o]; }
    if (b + 256 < nbh)  { rep += rep_part[o + 256];  att += att_part[o + 256]; }
    srep[b] = rep; satt[b] = att;
    __syncthreads();
    for (int s = 128; s > 0; s >>= 1) {
        if (b < s) { srep[b] += srep[b + s]; satt[b] += satt[b + s]; }
        __syncthreads();
    }
    if (b == 0) {
        float4 a  = objA[k];
        float4 b4 = objB[k];
        float cnt = a.w, qa = a.z, valid = b4.z;
        float vatt = valid * satt[0] * qa / fmaxf(cnt, 1.0f);
        float vrep = valid * srep[0] * qa / fmaxf((float)n - cnt, 1.0f);
        objC[k] = make_float4(vatt + vrep + b4.y + b4.x, valid, cnt, 0.f);
    }
}

// ---------------- Kernel D2: scalar finish
__global__ __launch_bounds__(256) void final2(
    const float4* __restrict__ objC,
    const float*  __restrict__ noise_part,
    float* __restrict__ out, int n)
{
    __shared__ float4 sred[256];
    int t = threadIdx.x;
    float4 c = objC[t];
    c.w = noise_part[t];
    sred[t] = c;
    __syncthreads();
    for (int s = 128; s > 0; s >>= 1) {
        if (t < s) {
            float4 x = sred[t], y = sred[t + s];
            sred[t] = make_float4(x.x + y.x, x.y + y.y, x.z + y.z, x.w + y.w);
        }
        __syncthreads();
    }
    if (t == 0) {
        float4 r = sred[0];
        float nv = fmaxf(r.y, 1.0f);                    // n_valid
        float nnoise = fmaxf((float)n - r.z, 1.0f);     // noise count
        out[0] = r.x / nv + r.w / nnoise;
    }
}

extern "C" void kernel_launch(void* const* d_in, const int* in_sizes, int n_in,
                              void* d_out, int out_size, void* d_ws, size_t ws_size,
                              hipStream_t stream) {
    const float*  pred_beta    = (const float*)d_in[0];
    const float2* pred_ccoords = (const float2*)d_in[1];
    const float*  pred_energy  = (const float*)d_in[2];
    const float2* pred_pos     = (const float2*)d_in[3];
    const float*  pred_time    = (const float*)d_in[4];
    const float2* pred_id2     = (const float2*)d_in[5];
    const float*  t_energy     = (const float*)d_in[6];
    const float2* t_pos        = (const float2*)d_in[7];
    const float*  t_time       = (const float*)d_in[8];
    const int*    t_idx        = (const int*)d_in[10];
    int n = in_sizes[0];
    int nbh = (n + 255) / 256;          // 391 for n=100000
    int hstr = (nbh + 8) & ~7;          // padded row stride (392)

    // workspace carve (16B-aligned)
    char* base = (char*)d_ws;
    size_t off = 0;
    u64*    pk_part    = (u64*)   (base + off); off += (size_t)KOBJ * B1 * 8;    // 512 KB
    float*  cnt_part   = (float*) (base + off); off += (size_t)KOBJ * B1 * 4;    // 256 KB
    float*  den_part   = (float*) (base + off); off += (size_t)KOBJ * B1 * 4;    // 256 KB
    float*  num_part   = (float*) (base + off); off += (size_t)KOBJ * B1 * 4;    // 256 KB
    float*  noise_part = (float*) (base + off); off += 256 * 4;
    float4* objA       = (float4*)(base + off); off += KOBJ * 16;
    float4* objB       = (float4*)(base + off); off += KOBJ * 16;
    float4* objC       = (float4*)(base + off); off += KOBJ * 16;
    float*  rep_part   = (float*) (base + off); off += (size_t)KOBJ * hstr * 4;  // ~400 KB
    float*  att_part   = (float*) (base + off); off += (size_t)KOBJ * hstr * 4;

    partials<<<B1, 256, 0, stream>>>(pred_beta, pred_energy, pred_pos, pred_time,
                                     pred_id2, t_energy, t_pos, t_time, t_idx,
                                     pk_part, cnt_part, den_part, num_part, noise_part, n);
    merge<<<KOBJ, 256, 0, stream>>>(pred_ccoords, pk_part, cnt_part, den_part, num_part,
                                    objA, objB);
    heavy<<<nbh, 256, 0, stream>>>(pred_beta, pred_ccoords, t_idx, objA,
                                   rep_part, att_part, n, hstr);
    final1<<<KOBJ, 256, 0, stream>>>(objA, objB, rep_part, att_part, objC, n, nbh, hstr);
    final2<<<1, 256, 0, stream>>>(objC, noise_part, (float*)d_out, n);
}